// Round 1
// baseline (33598.663 us; speedup 1.0000x reference)
//
#include <hip/hip_runtime.h>
#include <cstddef>

#define HID   512
#define G4    2048   // 4*HID
#define NB    32     // batch
#define SEQL  1024
#define INPD  512

__device__ __forceinline__ float sigm(float x) {
    return 1.0f / (1.0f + __expf(-x));
}
__device__ __forceinline__ float tanh_fast(float x) {
    float e = __expf(-2.0f * fabsf(x));
    float t = (1.0f - e) / (1.0f + e);
    return copysignf(t, x);
}

// W_hh [2048][512] -> W_hhT [512][2048], tiled transpose
__global__ __launch_bounds__(256) void transpose_whh(const float* __restrict__ w,
                                                     float* __restrict__ wt) {
    __shared__ float tile[32][33];
    int k0 = blockIdx.x * 32;   // 512/32 = 16
    int g0 = blockIdx.y * 32;   // 2048/32 = 64
    int tx = threadIdx.x;       // 32
    int ty = threadIdx.y;       // 8
    #pragma unroll
    for (int i = ty; i < 32; i += 8)
        tile[i][tx] = w[(size_t)(g0 + i) * HID + k0 + tx];      // coalesced along k
    __syncthreads();
    #pragma unroll
    for (int i = ty; i < 32; i += 8)
        wt[(size_t)(k0 + i) * G4 + g0 + tx] = tile[tx][i];      // coalesced along g
}

// x_proj chunk GEMM: xbuf[m][n] = sum_k inputs[row(m)][k] * w_ih[n][k] + bih[n] + bhh[n]
// m enumerates (b, tloc) b-major; M = NB*SC, N = 2048, K = 512.
__global__ __launch_bounds__(256) void xproj_gemm(const float* __restrict__ x,
                                                  const float* __restrict__ wih,
                                                  const float* __restrict__ bih,
                                                  const float* __restrict__ bhh,
                                                  float* __restrict__ xbuf,
                                                  int chunk, int SC) {
    __shared__ float As[16][68];  // [k][m_local]
    __shared__ float Bs[16][68];  // [k][n_local]
    const int m0 = blockIdx.x * 64;
    const int n0 = blockIdx.y * 64;
    const int tid = threadIdx.x;
    const int tx = tid % 16;       // n-dir
    const int ty = tid / 16;       // m-dir
    const int lr  = tid / 4;       // load row 0..63
    const int lc4 = tid % 4;       // which float4 of 16 k's

    float acc[4][4] = {};

    // precompute per-thread A source row
    const int m = m0 + lr;
    const int b  = m / SC;
    const int tl = m % SC;
    const float* arow_base = x + ((size_t)b * SEQL + (size_t)chunk * SC + tl) * INPD + lc4 * 4;
    const float* brow_base = wih + (size_t)(n0 + lr) * INPD + lc4 * 4;

    for (int k0 = 0; k0 < 512; k0 += 16) {
        float4 a4 = *(const float4*)(arow_base + k0);
        float4 b4 = *(const float4*)(brow_base + k0);
        As[lc4 * 4 + 0][lr] = a4.x;
        As[lc4 * 4 + 1][lr] = a4.y;
        As[lc4 * 4 + 2][lr] = a4.z;
        As[lc4 * 4 + 3][lr] = a4.w;
        Bs[lc4 * 4 + 0][lr] = b4.x;
        Bs[lc4 * 4 + 1][lr] = b4.y;
        Bs[lc4 * 4 + 2][lr] = b4.z;
        Bs[lc4 * 4 + 3][lr] = b4.w;
        __syncthreads();
        #pragma unroll
        for (int kk = 0; kk < 16; ++kk) {
            float4 av = *(const float4*)&As[kk][ty * 4];
            float4 bv = *(const float4*)&Bs[kk][tx * 4];
            float a[4] = {av.x, av.y, av.z, av.w};
            float bb[4] = {bv.x, bv.y, bv.z, bv.w};
            #pragma unroll
            for (int i = 0; i < 4; ++i)
                #pragma unroll
                for (int j = 0; j < 4; ++j)
                    acc[i][j] = fmaf(a[i], bb[j], acc[i][j]);
        }
        __syncthreads();
    }

    #pragma unroll
    for (int i = 0; i < 4; ++i) {
        int mo = m0 + ty * 4 + i;
        float* orow = xbuf + (size_t)mo * G4;
        #pragma unroll
        for (int j = 0; j < 4; ++j) {
            int n = n0 + tx * 4 + j;
            orow[n] = acc[i][j] + bih[n] + bhh[n];
        }
    }
}

// Recurrence over one chunk. One block per batch element, 512 threads.
// Thread t accumulates gates 4t..4t+3; thread t also owns hidden unit t for the cell.
__global__ __launch_bounds__(512) void lstm_chunk(const float* __restrict__ wt,   // [512][2048]
                                                  const float* __restrict__ xbuf, // [NB][SC][2048]
                                                  const float* __restrict__ hin,  // [NB][512]
                                                  const float* __restrict__ cin,
                                                  float* __restrict__ hstate,
                                                  float* __restrict__ cstate,
                                                  float* __restrict__ out,        // [NB][SEQ][512]
                                                  int chunk, int SC) {
    __shared__ float h_lds[HID];
    __shared__ float g_lds[G4];
    const int b = blockIdx.x;
    const int t = threadIdx.x;

    h_lds[t] = hin[b * HID + t];
    float c = cin[b * HID + t];
    __syncthreads();

    const float* wtp  = wt + 4 * t;
    const float* xrow = xbuf + (size_t)b * SC * G4 + 4 * t;
    float* orow = out + ((size_t)b * SEQL + (size_t)chunk * SC) * HID;

    for (int s = 0; s < SC; ++s) {
        float4 acc = *(const float4*)xrow;
        const float* wp = wtp;
        #pragma unroll 4
        for (int k = 0; k < HID; k += 4) {
            float4 h4 = *(const float4*)&h_lds[k];
            float4 w0 = *(const float4*)(wp);
            float4 w1 = *(const float4*)(wp + G4);
            float4 w2 = *(const float4*)(wp + 2 * G4);
            float4 w3 = *(const float4*)(wp + 3 * G4);
            acc.x = fmaf(h4.x, w0.x, acc.x);
            acc.y = fmaf(h4.x, w0.y, acc.y);
            acc.z = fmaf(h4.x, w0.z, acc.z);
            acc.w = fmaf(h4.x, w0.w, acc.w);
            acc.x = fmaf(h4.y, w1.x, acc.x);
            acc.y = fmaf(h4.y, w1.y, acc.y);
            acc.z = fmaf(h4.y, w1.z, acc.z);
            acc.w = fmaf(h4.y, w1.w, acc.w);
            acc.x = fmaf(h4.z, w2.x, acc.x);
            acc.y = fmaf(h4.z, w2.y, acc.y);
            acc.z = fmaf(h4.z, w2.z, acc.z);
            acc.w = fmaf(h4.z, w2.w, acc.w);
            acc.x = fmaf(h4.w, w3.x, acc.x);
            acc.y = fmaf(h4.w, w3.y, acc.y);
            acc.z = fmaf(h4.w, w3.z, acc.z);
            acc.w = fmaf(h4.w, w3.w, acc.w);
            wp += 4 * G4;
        }
        *(float4*)&g_lds[4 * t] = acc;
        __syncthreads();

        float i_t = sigm(g_lds[t]);
        float f_t = sigm(g_lds[HID + t]);
        float g_t = tanh_fast(g_lds[2 * HID + t]);
        float o_t = sigm(g_lds[3 * HID + t]);
        c = fmaf(f_t, c, i_t * g_t);
        float hnew = o_t * tanh_fast(c);

        h_lds[t] = hnew;
        orow[t] = hnew;
        __syncthreads();

        orow += HID;
        xrow += G4;
    }

    hstate[b * HID + t] = h_lds[t];
    cstate[b * HID + t] = c;
}

__global__ __launch_bounds__(256) void finalize(const float* __restrict__ hs,
                                                const float* __restrict__ cs,
                                                float* __restrict__ out) {
    int i = blockIdx.x * blockDim.x + threadIdx.x;
    size_t base = (size_t)NB * SEQL * HID;
    if (i < NB * HID) {
        out[base + i] = hs[i];
        out[base + NB * HID + i] = cs[i];
    }
}

extern "C" void kernel_launch(void* const* d_in, const int* in_sizes, int n_in,
                              void* d_out, int out_size, void* d_ws, size_t ws_size,
                              hipStream_t stream) {
    const float* x   = (const float*)d_in[0];
    const float* h0  = (const float*)d_in[1];
    const float* c0  = (const float*)d_in[2];
    const float* wih = (const float*)d_in[3];
    const float* whh = (const float*)d_in[4];
    const float* bih = (const float*)d_in[5];
    const float* bhh = (const float*)d_in[6];
    float* out = (float*)d_out;

    char* ws = (char*)d_ws;
    float* wt     = (float*)ws;                                  // 4 MB
    float* hstate = (float*)(ws + (size_t)4 * 1024 * 1024);      // 64 KB
    float* cstate = hstate + NB * HID;                           // 64 KB
    float* xbuf   = cstate + NB * HID;

    size_t fixed = (size_t)4 * 1024 * 1024 + (size_t)2 * NB * HID * sizeof(float);
    int SC = 128;
    while (SC > 2 && fixed + (size_t)NB * SC * G4 * sizeof(float) > ws_size) SC >>= 1;

    transpose_whh<<<dim3(16, 64), dim3(32, 8), 0, stream>>>(whh, wt);

    int nchunks = SEQL / SC;
    for (int c = 0; c < nchunks; ++c) {
        dim3 g(NB * SC / 64, G4 / 64);
        xproj_gemm<<<g, 256, 0, stream>>>(x, wih, bih, bhh, xbuf, c, SC);
        const float* hin = (c == 0) ? h0 : hstate;
        const float* cin = (c == 0) ? c0 : cstate;
        lstm_chunk<<<NB, 512, 0, stream>>>(wt, xbuf, hin, cin, hstate, cstate, out, c, SC);
    }

    finalize<<<(NB * HID + 255) / 256, 256, 0, stream>>>(hstate, cstate, out);
}